// Round 5
// baseline (256.294 us; speedup 1.0000x reference)
//
#include <hip/hip_runtime.h>
#include <math.h>

#define NUM_HEADS 32
#define HEAD_DIM 128
#define NUM_KV_HEADS 8
#define SCALE 0.08838834764831845f
#define EPS 1e-8f
#define MAX_SEG 512
#define QT 32            // q rows per block
#define BLK 512          // 8 waves
#define SEGC_MAX 16      // 512 keys / 32
#define PD_CHUNKS 4
#define SAL_PAD 576
#define PB_STRIDE 520    // bf16 elems: 1040 B, %16==0, %128==16 -> conflict-free b128 phases
#define PD_STRIDE 136    // 272 B: %16==0, %128==16
#define TLD 130
#define CD (NUM_HEADS * HEAD_DIM)

typedef __bf16 bf16x8 __attribute__((ext_vector_type(8)));
typedef __bf16 bf16x4 __attribute__((ext_vector_type(4)));
typedef float  f32x4  __attribute__((ext_vector_type(4)));

__device__ __forceinline__ int lower_bound_i(const int* __restrict__ a, int n, int key) {
    int lo = 0, hi = n;
    while (lo < hi) { int mid = (lo + hi) >> 1; if (a[mid] < key) lo = mid + 1; else hi = mid; }
    return lo;
}
__device__ __forceinline__ int bsearch_eq(const int* __restrict__ a, int n, int key) {
    int lo = lower_bound_i(a, n, key);
    return (lo < n && a[lo] == key) ? lo : -1;
}

// ---------------- mega-prep: conv K | build vnewT | build vdT ----------------
__global__ void prep(const float* __restrict__ k, const float* __restrict__ v,
                     const float* __restrict__ vc, const int* __restrict__ idx,
                     __bf16* __restrict__ kb, __bf16* __restrict__ vnewT,
                     __bf16* __restrict__ vdT, int T, int Tpad, int n_sal,
                     int nb_conv, int nb_vt) {
    __shared__ __bf16 tile[64 * TLD];
    __shared__ int sal_of[64];
    const int b = blockIdx.x;
    const int tid = threadIdx.x;

    if (b < nb_conv) {
        int i = b * 256 + tid;
        int n8 = T * NUM_KV_HEADS * HEAD_DIM / 8;
        if (i < n8) {
            const float4* s4 = (const float4*)(k + (size_t)i * 8);
            float4 a = s4[0], bb = s4[1];
            bf16x8 o;
            o[0]=(__bf16)a.x; o[1]=(__bf16)a.y; o[2]=(__bf16)a.z; o[3]=(__bf16)a.w;
            o[4]=(__bf16)bb.x; o[5]=(__bf16)bb.y; o[6]=(__bf16)bb.z; o[7]=(__bf16)bb.w;
            *(bf16x8*)(kb + (size_t)i * 8) = o;
        }
        return;
    }
    if (b < nb_conv + nb_vt * NUM_KV_HEADS) {
        const int bb = b - nb_conv;
        const int kv = bb / nb_vt;
        const int r0 = (bb % nb_vt) * 64;
        if (tid < 64) sal_of[tid] = bsearch_eq(idx, n_sal, r0 + tid);
        __syncthreads();
        for (int ii = tid; ii < 64 * 32; ii += 256) {
            int r = ii >> 5, c4 = ii & 31;
            int row = r0 + r;
            float4 f = {0.f, 0.f, 0.f, 0.f};
            if (row < T) {
                int s2 = sal_of[r];
                const float* src = (s2 >= 0)
                    ? v  + ((size_t)s2  * NUM_KV_HEADS + kv) * HEAD_DIM
                    : vc + ((size_t)row * NUM_KV_HEADS + kv) * HEAD_DIM;
                f = *(const float4*)(src + c4 * 4);
            }
            __bf16* tp = &tile[r * TLD + c4 * 4];
            tp[0] = (__bf16)f.x; tp[1] = (__bf16)f.y; tp[2] = (__bf16)f.z; tp[3] = (__bf16)f.w;
        }
        __syncthreads();
        for (int ii = tid; ii < 128 * 8; ii += 256) {
            int d = ii >> 3, rg = ii & 7;
            int row_out = r0 + rg * 8;
            if (row_out < Tpad) {
                bf16x8 o;
#pragma unroll
                for (int j = 0; j < 8; j++) o[j] = tile[(rg * 8 + j) * TLD + d];
                *(bf16x8*)(vnewT + ((size_t)kv * HEAD_DIM + d) * Tpad + row_out) = o;
            }
        }
        return;
    }
    {
        const int bb = b - nb_conv - nb_vt * NUM_KV_HEADS;
        const int nvd = SAL_PAD / 64;
        const int kv = bb / nvd;
        const int s0 = (bb % nvd) * 64;
        for (int ii = tid; ii < 64 * 32; ii += 256) {
            int r = ii >> 5, c4 = ii & 31;
            int s = s0 + r;
            float4 f = {0.f, 0.f, 0.f, 0.f};
            if (s < n_sal) {
                int row = idx[s];
                float4 a = *(const float4*)(v  + ((size_t)s   * NUM_KV_HEADS + kv) * HEAD_DIM + c4 * 4);
                float4 bb2 = *(const float4*)(vc + ((size_t)row * NUM_KV_HEADS + kv) * HEAD_DIM + c4 * 4);
                f.x = a.x - bb2.x; f.y = a.y - bb2.y; f.z = a.z - bb2.z; f.w = a.w - bb2.w;
            }
            __bf16* tp = &tile[r * TLD + c4 * 4];
            tp[0] = (__bf16)f.x; tp[1] = (__bf16)f.y; tp[2] = (__bf16)f.z; tp[3] = (__bf16)f.w;
        }
        __syncthreads();
        for (int ii = tid; ii < 128 * 8; ii += 256) {
            int d = ii >> 3, rg = ii & 7;
            bf16x8 o;
#pragma unroll
            for (int j = 0; j < 8; j++) o[j] = tile[(rg * 8 + j) * TLD + d];
            *(bf16x8*)(vdT + ((size_t)kv * HEAD_DIM + d) * SAL_PAD + s0 + rg * 8) = o;
        }
    }
}

// ---------------- main fused attention ----------------
__global__ __launch_bounds__(BLK, 4)
void attn_mfma(const float* __restrict__ q, const __bf16* __restrict__ kb,
               const __bf16* __restrict__ vnewT, const __bf16* __restrict__ vdT,
               const float* __restrict__ c_cache, const int* __restrict__ cu,
               const int* __restrict__ idx, float* __restrict__ out_c,
               float* __restrict__ cospart, int T, int Tpad, int n_seq, int n_sal) {
    const int qt    = blockIdx.x;
    const int h     = blockIdx.y;
    const int kvh   = h >> 2;
    const int qrow0 = qt * QT;
    const int tid   = threadIdx.x;
    const int wave  = tid >> 6;
    const int lane  = tid & 63;
    const int lm    = lane & 15;
    const int quad  = lane >> 4;

    __shared__ __align__(16) __bf16 Pb[QT * PB_STRIDE];   // row-major [q][key]
    __shared__ __align__(16) __bf16 Pd[QT * PD_STRIDE];   // row-major [q][srel]
    __shared__ int   scol[MAX_SEG];
    __shared__ float wred[8 * QT];
    __shared__ float linv[QT];
    __shared__ int   salrow[QT];

    int seg_start = 0, seg_end = T;
    for (int s = 0; s < n_seq; s++) {
        int a = cu[s], bnd = cu[s + 1];
        if (qrow0 >= a && qrow0 < bnd) { seg_start = a; seg_end = bnd; }
    }
    const int seg_len = seg_end - seg_start;
    const int s_lo = lower_bound_i(idx, n_sal, seg_start);
    const int s_hi = lower_bound_i(idx, n_sal, seg_end);
    const int nss  = s_hi - s_lo;
    const int ntiles = (seg_len + 15) >> 4;
    const int SEGC   = (seg_len + 31) >> 5;
    const int ndc    = (nss + 31) >> 5;
    const bool al8   = ((s_lo & 7) == 0);
    const bool fast  = (SEGC == SEGC_MAX) && (ndc <= PD_CHUNKS);

    const int dim = wave * 16 + lm;
    const __bf16* vbase  = vnewT + ((size_t)kvh * HEAD_DIM + dim) * Tpad + seg_start + quad * 8;
    const __bf16* vdbase = vdT + ((size_t)kvh * HEAD_DIM + dim) * SAL_PAD + s_lo + quad * 8;
    const __bf16* pb0 = &Pb[lm * PB_STRIDE + quad * 8];
    const __bf16* pb1 = &Pb[(16 + lm) * PB_STRIDE + quad * 8];

    if (tid < QT) salrow[tid] = bsearch_eq(idx, n_sal, qrow0 + tid);
    for (int s = tid; s < nss; s += BLK) scol[s] = idx[s_lo + s] - seg_start;
    if (ntiles * 16 < SEGC * 32) {   // zero tail half-chunk
        for (int ii = tid; ii < QT * 16; ii += BLK) {
            int row = ii >> 4, col = ntiles * 16 + (ii & 15);
            Pb[row * PB_STRIDE + col] = (__bf16)0.f;
        }
    }

    // ---- Q fragments (rows rt*16+lm, k = cc*32 + quad*8 + j) ----
    bf16x8 aq[2][4];
#pragma unroll
    for (int rt = 0; rt < 2; rt++) {
        const float* qp = q + ((size_t)(qrow0 + rt * 16 + lm) * NUM_HEADS + h) * HEAD_DIM + quad * 8;
#pragma unroll
        for (int cc = 0; cc < 4; cc++) {
            float4 f0 = *(const float4*)(qp + cc * 32);
            float4 f1 = *(const float4*)(qp + cc * 32 + 4);
            bf16x8 a;
            a[0]=(__bf16)f0.x; a[1]=(__bf16)f0.y; a[2]=(__bf16)f0.z; a[3]=(__bf16)f0.w;
            a[4]=(__bf16)f1.x; a[5]=(__bf16)f1.y; a[6]=(__bf16)f1.z; a[7]=(__bf16)f1.w;
            aq[rt][cc] = a;
        }
    }

    // ---- K prefetch: all 4 tiles of this wave up front ----
    bf16x8 bk[4][4];
#pragma unroll
    for (int tt = 0; tt < 4; tt++) {
        const int t = wave * 4 + tt;
        if (t < ntiles) {
            int key = seg_start + t * 16 + lm;
            if (key >= seg_start + seg_len) key = seg_start + seg_len - 1;
            const __bf16* kp = kb + ((size_t)key * NUM_KV_HEADS + kvh) * HEAD_DIM + quad * 8;
#pragma unroll
            for (int cc = 0; cc < 4; cc++) bk[tt][cc] = *(const bf16x8*)(kp + cc * 32);
        }
    }

    // ---- QK^T (A=K, B=Q): D[m=key][n=q]; exp in regs; packed b64 stores ----
    float ps[2] = {0.f, 0.f};
#pragma unroll
    for (int tt = 0; tt < 4; tt++) {
        const int t = wave * 4 + tt;
        if (t < ntiles) {
            f32x4 acc[2] = {{0.f,0.f,0.f,0.f},{0.f,0.f,0.f,0.f}};
#pragma unroll
            for (int cc = 0; cc < 4; cc++) {
                acc[0] = __builtin_amdgcn_mfma_f32_16x16x32_bf16(bk[tt][cc], aq[0][cc], acc[0], 0, 0, 0);
                acc[1] = __builtin_amdgcn_mfma_f32_16x16x32_bf16(bk[tt][cc], aq[1][cc], acc[1], 0, 0, 0);
            }
#pragma unroll
            for (int rt = 0; rt < 2; rt++) {
                bf16x4 pk;
#pragma unroll
                for (int r = 0; r < 4; r++) {
                    const int kl = t * 16 + quad * 4 + r;
                    float e = (kl < seg_len) ? __expf(acc[rt][r] * SCALE) : 0.f;
                    ps[rt] += e;
                    pk[r] = (__bf16)e;
                }
                *(bf16x4*)&Pb[(rt * 16 + lm) * PB_STRIDE + t * 16 + quad * 4] = pk;
            }
        }
    }
#pragma unroll
    for (int m = 16; m <= 32; m <<= 1) {
        ps[0] += __shfl_xor(ps[0], m, 64);
        ps[1] += __shfl_xor(ps[1], m, 64);
    }
    if (quad == 0) {
        wred[wave * QT + lm]      = ps[0];
        wred[wave * QT + 16 + lm] = ps[1];
    }

    // ---- epilogue c_cache loads: in flight across the PV phase ----
    const float* cbase = c_cache + (size_t)qrow0 * CD + h * HEAD_DIM + dim;
    float cold[2][4];
#pragma unroll
    for (int rt = 0; rt < 2; rt++)
#pragma unroll
        for (int r = 0; r < 4; r++)
            cold[rt][r] = cbase[(size_t)(rt * 16 + quad * 4 + r) * CD];

    f32x4 accF[2] = {{0.f,0.f,0.f,0.f},{0.f,0.f,0.f,0.f}};
    f32x4 accD[2] = {{0.f,0.f,0.f,0.f},{0.f,0.f,0.f,0.f}};

    if (fast) {
        // ---- prefetch ALL PV operands into registers BEFORE the barrier ----
        bf16x8 vreg[SEGC_MAX];
#pragma unroll
        for (int cc = 0; cc < SEGC_MAX; cc++) vreg[cc] = *(const bf16x8*)(vbase + cc * 32);
        bf16x8 vdreg[PD_CHUNKS];
#pragma unroll
        for (int dc = 0; dc < PD_CHUNKS; dc++) {
            if (dc < ndc) {
                const __bf16* vp = vdbase + dc * 32;
                if (al8) vdreg[dc] = *(const bf16x8*)vp;
                else {
#pragma unroll
                    for (int j = 0; j < 8; j++) vdreg[dc][j] = vp[j];
                }
            }
        }
        __syncthreads();   // Pb, wred, scol complete
        if (tid < QT) {
            float s = 0.f;
#pragma unroll
            for (int w = 0; w < 8; w++) s += wred[w * QT + tid];
            linv[tid] = 1.f / s;
        }
        // gather salient P columns into Pd
        for (int ii = tid; ii < QT * PD_CHUNKS * 32; ii += BLK) {
            int row = ii >> 7, srel = ii & 127;
            __bf16 e = (__bf16)0.f;
            if (srel < nss) e = Pb[row * PB_STRIDE + scol[srel]];
            Pd[row * PD_STRIDE + srel] = e;
        }
        __syncthreads();   // Pd + linv ready
        // ---- pure LDS+MFMA, 4 independent chains ----
#pragma unroll
        for (int cc = 0; cc < SEGC_MAX; cc++) {
            bf16x8 a0 = *(const bf16x8*)(pb0 + cc * 32);
            bf16x8 a1 = *(const bf16x8*)(pb1 + cc * 32);
            accF[0] = __builtin_amdgcn_mfma_f32_16x16x32_bf16(a0, vreg[cc], accF[0], 0, 0, 0);
            accF[1] = __builtin_amdgcn_mfma_f32_16x16x32_bf16(a1, vreg[cc], accF[1], 0, 0, 0);
            if (cc < PD_CHUNKS) {
                if (cc * 32 < nss) {
                    bf16x8 d0 = *(const bf16x8*)&Pd[lm * PD_STRIDE + cc * 32 + quad * 8];
                    bf16x8 d1 = *(const bf16x8*)&Pd[(16 + lm) * PD_STRIDE + cc * 32 + quad * 8];
                    accD[0] = __builtin_amdgcn_mfma_f32_16x16x32_bf16(d0, vdreg[cc], accD[0], 0, 0, 0);
                    accD[1] = __builtin_amdgcn_mfma_f32_16x16x32_bf16(d1, vdreg[cc], accD[1], 0, 0, 0);
                }
            }
        }
        __syncthreads();   // Pd reads done (cp reuse below)
    } else {
        // ---- generic fallback (seg_len != 512-class): round-4 structure ----
        __syncthreads();
        if (tid < QT) {
            float s = 0.f;
#pragma unroll
            for (int w = 0; w < 8; w++) s += wred[w * QT + tid];
            linv[tid] = 1.f / s;
        }
        for (int cc = 0; cc < SEGC; cc++) {
            bf16x8 a0 = *(const bf16x8*)(pb0 + cc * 32);
            bf16x8 a1 = *(const bf16x8*)(pb1 + cc * 32);
            bf16x8 bv = *(const bf16x8*)(vbase + cc * 32);
            accF[0] = __builtin_amdgcn_mfma_f32_16x16x32_bf16(a0, bv, accF[0], 0, 0, 0);
            accF[1] = __builtin_amdgcn_mfma_f32_16x16x32_bf16(a1, bv, accF[1], 0, 0, 0);
        }
        for (int base = 0; base < ndc; base += PD_CHUNKS) {
            const int bc = min(PD_CHUNKS, ndc - base);
            __syncthreads();
            for (int ii = tid; ii < QT * PD_CHUNKS * 32; ii += BLK) {
                int row = ii >> 7, srel = ii & 127;
                int s = base * 32 + srel;
                __bf16 e = (__bf16)0.f;
                if (srel < bc * 32 && s < nss) e = Pb[row * PB_STRIDE + scol[s]];
                Pd[row * PD_STRIDE + srel] = e;
            }
            __syncthreads();
#pragma unroll
            for (int dc = 0; dc < PD_CHUNKS; dc++) {
                if (dc < bc) {
                    bf16x8 d0 = *(const bf16x8*)&Pd[lm * PD_STRIDE + dc * 32 + quad * 8];
                    bf16x8 d1 = *(const bf16x8*)&Pd[(16 + lm) * PD_STRIDE + dc * 32 + quad * 8];
                    const __bf16* vp = vdbase + (base + dc) * 32;
                    bf16x8 bv;
                    if (al8) bv = *(const bf16x8*)vp;
                    else {
#pragma unroll
                        for (int j = 0; j < 8; j++) bv[j] = vp[j];
                    }
                    accD[0] = __builtin_amdgcn_mfma_f32_16x16x32_bf16(d0, bv, accD[0], 0, 0, 0);
                    accD[1] = __builtin_amdgcn_mfma_f32_16x16x32_bf16(d1, bv, accD[1], 0, 0, 0);
                }
            }
        }
        __syncthreads();
    }

    // ---- epilogue: outputs + cosine partials ----
    float* cp = (float*)Pd;   // cp[wave][3][32]
    float* obase = out_c + (size_t)qrow0 * CD + h * HEAD_DIM + dim;
#pragma unroll
    for (int rt = 0; rt < 2; rt++) {
#pragma unroll
        for (int r = 0; r < 4; r++) {
            const int row = rt * 16 + quad * 4 + r;
            const float c_old = cold[rt][r];
            const float li = linv[row];
            float o;
            if (salrow[row] >= 0) o = accF[rt][r] * li;
            else                  o = c_old + accD[rt][r] * li;
            obase[(size_t)row * CD] = o;
            float xn = o * c_old, xc = c_old * c_old, xd = o * o;
#pragma unroll
            for (int m = 1; m <= 8; m <<= 1) {
                xn += __shfl_xor(xn, m, 64);
                xc += __shfl_xor(xc, m, 64);
                xd += __shfl_xor(xd, m, 64);
            }
            if (lm == 0) {
                cp[(wave * 3 + 0) * QT + row] = xn;
                cp[(wave * 3 + 1) * QT + row] = xc;
                cp[(wave * 3 + 2) * QT + row] = xd;
            }
        }
    }
    __syncthreads();
    for (int ii = tid; ii < 3 * QT; ii += BLK) {
        int c = ii >> 5, row = ii & 31;
        float s = 0.f;
#pragma unroll
        for (int w = 0; w < 8; w++) s += cp[(w * 3 + c) * QT + row];
        cospart[((size_t)(qrow0 + row) * NUM_HEADS + h) * 3 + c] = s;
    }
}

// ---------------- cos finalize ----------------
__global__ void cos_finalize(const float* __restrict__ cospart, float* __restrict__ out_cos, int T) {
    int i = blockIdx.x * blockDim.x + threadIdx.x;
    if (i < T) {
        const float* p = cospart + (size_t)i * NUM_HEADS * 3;
        float n = 0.f, c = 0.f, d = 0.f;
#pragma unroll
        for (int h2 = 0; h2 < NUM_HEADS; h2++) {
            n += p[h2 * 3 + 0]; c += p[h2 * 3 + 1]; d += p[h2 * 3 + 2];
        }
        out_cos[i] = n / (sqrtf(c) * sqrtf(d) + EPS);
    }
}

extern "C" void kernel_launch(void* const* d_in, const int* in_sizes, int n_in,
                              void* d_out, int out_size, void* d_ws, size_t ws_size,
                              hipStream_t stream) {
    const float* q       = (const float*)d_in[0];
    const float* k       = (const float*)d_in[1];
    const float* v       = (const float*)d_in[2];
    const float* v_cache = (const float*)d_in[3];
    const float* c_cache = (const float*)d_in[4];
    const int*   idx     = (const int*)d_in[5];
    const int*   cu      = (const int*)d_in[6];

    const int T     = in_sizes[0] / CD;
    const int n_sal = in_sizes[5];
    const int n_seq = in_sizes[6] - 1;
    const int Tpad  = T + 32;

    float* out_c   = (float*)d_out;
    float* out_cos = out_c + (size_t)T * CD;

    char* wsp = (char*)d_ws;
    size_t off = 0;
    __bf16* kb = (__bf16*)(wsp + off);
    off += (((size_t)T * NUM_KV_HEADS * HEAD_DIM * 2) + 255) & ~(size_t)255;
    __bf16* vnewT = (__bf16*)(wsp + off);
    off += (((size_t)NUM_KV_HEADS * HEAD_DIM * Tpad * 2) + 255) & ~(size_t)255;
    __bf16* vdT = (__bf16*)(wsp + off);
    off += ((size_t)NUM_KV_HEADS * HEAD_DIM * SAL_PAD * 2 + 255) & ~(size_t)255;
    float* cospart = (float*)(wsp + off);
    off += ((size_t)T * NUM_HEADS * 3 * 4 + 255) & ~(size_t)255;
    (void)ws_size;

    const int nb_conv = (T * NUM_KV_HEADS * HEAD_DIM / 8 + 255) / 256;
    const int nb_vt   = (Tpad + 63) / 64;
    const int nb_vd   = SAL_PAD / 64;
    const int nb_tot  = nb_conv + nb_vt * NUM_KV_HEADS + nb_vd * NUM_KV_HEADS;

    prep<<<nb_tot, 256, 0, stream>>>(k, v, v_cache, idx, kb, vnewT, vdT,
                                     T, Tpad, n_sal, nb_conv, nb_vt);

    dim3 grid(T / QT, NUM_HEADS);
    attn_mfma<<<grid, BLK, 0, stream>>>(q, kb, vnewT, vdT, c_cache, cu, idx,
                                        out_c, cospart, T, Tpad, n_seq, n_sal);

    cos_finalize<<<(T + 255) / 256, 256, 0, stream>>>(cospart, out_cos, T);
}